// Round 7
// baseline (2473.098 us; speedup 1.0000x reference)
//
#include <hip/hip_runtime.h>
#include <hip/hip_bf16.h>
#include <cstdint>
#include <cstddef>

// ---------------------------------------------------------------------------
// Transformer_78941498901000 — round 6: re-fused attn+proj+LN built for
// occupancy: B direct from L2 (no Bs staging), subtiled conflict-free As,
// 66 KB LDS -> 2 blocks/CU, VGPR capped for 16 waves/CU.
// B=512 T=128 C=512 H=8 D=64 L=6 V=13, BT=65536
// d_out = logits f32 [851968] ++ loss f32 [1]
//
// ws layout (bytes):
//   x_bf  @ 0          : bf16 [BT,512]       67,108,864   (residual stream)
//   wqkvT @ 67,108,864 : bf16 [L][1536][512]  9,437,184   (n-major, k-minor)
//   woT   @ 76,546,048 : bf16 [L][512][512]   3,145,728
//   dyn   @ 79,691,776 : qkv_c (3072 B/row)
// R = largest {65536..1024} with 79,691,776 + 3072*R <= ws_size
// ---------------------------------------------------------------------------

typedef __attribute__((ext_vector_type(8))) short short8;
typedef __attribute__((ext_vector_type(4))) float f32x4;

__device__ __forceinline__ float bf2f(ushort u) {
    return __uint_as_float(((unsigned int)u) << 16);
}
__device__ __forceinline__ ushort f2bf(float f) {
    unsigned int x = __float_as_uint(f);
    unsigned int r = (x + 0x7fffu + ((x >> 16) & 1u)) >> 16;  // RNE
    return (ushort)r;
}
// async global->LDS, 16B per lane; dst must be wave-uniform base (lane*16 HW)
__device__ __forceinline__ void gload_lds16(const void* g, void* l) {
    __builtin_amdgcn_global_load_lds(
        (const __attribute__((address_space(1))) void*)g,
        (__attribute__((address_space(3))) void*)l, 16, 0, 0);
}

// ---------------- weight prep: f32 [K][N] -> bf16 [N][K] -------------------
__global__ void prep_weights(const float* __restrict__ Wq, const float* __restrict__ Wk,
                             const float* __restrict__ Wv, const float* __restrict__ Wo,
                             ushort* __restrict__ wqkvT, ushort* __restrict__ woT) {
    const int QKV_TOT = 6 * 1536 * 512;   // 4,718,592
    const int O_TOT   = 6 * 512 * 512;    // 1,572,864
    size_t idx = (size_t)blockIdx.x * 256 + threadIdx.x;
    if (idx < (size_t)QKV_TOT) {
        int k = (int)(idx & 511);
        int n = (int)((idx >> 9) % 1536);
        int l = (int)(idx / (1536 * 512));
        size_t base = (size_t)l * 512 * 512 + (size_t)k * 512;
        float v;
        if (n < 512)        v = Wq[base + n];
        else if (n < 1024)  v = Wk[base + (n - 512)];
        else                v = Wv[base + (n - 1024)];
        wqkvT[idx] = f2bf(v);
    } else if (idx < (size_t)(QKV_TOT + O_TOT)) {
        size_t j = idx - QKV_TOT;
        int k = (int)(j & 511);
        int n = (int)((j >> 9) & 511);
        int l = (int)(j / (512 * 512));
        woT[j] = f2bf(Wo[(size_t)l * 512 * 512 + (size_t)k * 512 + n]);
    }
}

// ---------------- embedding: x = bf16(wte[tok] + wpe[t]) -------------------
__global__ __launch_bounds__(256) void embed_kernel(const int* __restrict__ tok,
                                                    const float* __restrict__ wte,
                                                    const float* __restrict__ wpe,
                                                    ushort* __restrict__ xbf) {
    size_t idx = (size_t)blockIdx.x * 256 + threadIdx.x;  // one short8 per thread
    size_t row = idx >> 6;              // 64 chunks of 8 per row
    int c8 = (int)(idx & 63);
    int t = (int)(row & 127);
    int v = tok[row];
    const float* ep = wte + (size_t)v * 512 + c8 * 8;
    const float* pp = wpe + (size_t)t * 512 + c8 * 8;
    float4 e0 = *(const float4*)ep, e1 = *(const float4*)(ep + 4);
    float4 p0 = *(const float4*)pp, p1 = *(const float4*)(pp + 4);
    float s[8] = {e0.x + p0.x, e0.y + p0.y, e0.z + p0.z, e0.w + p0.w,
                  e1.x + p1.x, e1.y + p1.y, e1.z + p1.z, e1.w + p1.w};
    short8 o;
    #pragma unroll
    for (int j = 0; j < 8; j++) o[j] = (short)f2bf(s[j]);
    *(short8*)(xbf + row * 512 + c8 * 8) = o;
}

// ---------------- QKV GEMM: qkv = A[M,512] @ Bt[1536,512]^T + bias ---------
// 128x128 tile, BK=64, 4 waves, double-buffered global_load_lds, XCD-chunked
// grid swizzle. (unchanged from round 5 — measured 97 us, FETCH 27 MB)
__global__ __launch_bounds__(256) void gemm_qkv_kernel(
    const ushort* __restrict__ A, const ushort* __restrict__ Bt, int nm,
    const float* __restrict__ b0, const float* __restrict__ b1,
    const float* __restrict__ b2, ushort* __restrict__ obf) {
    __shared__ alignas(16) ushort As[2][128 * 64];   // 2 x 16 KB
    __shared__ alignas(16) ushort Bs[2][128 * 64];   // 2 x 16 KB
    const int tid = threadIdx.x;
    const int lane = tid & 63;
    const int wave = tid >> 6;
    const int bid = blockIdx.x;
    const int xcd = bid & 7;
    const int j = bid >> 3;
    const int m0 = ((j / 12) * 8 + xcd) * 128;
    const int n0 = (j % 12) * 128;
    const int wm = (wave >> 1) * 64;
    const int wn = (wave & 1) * 64;
    const int r = lane & 15;
    const int kq = (lane >> 4) * 8;
    const ushort* Ab = A  + (size_t)m0 * 512;
    const ushort* Bb = Bt + (size_t)n0 * 512;
    f32x4 acc[4][4] = {};

    auto stage = [&](int t, int b) {
        const ushort* At = Ab + t * 64;
        const ushort* Bt2 = Bb + t * 64;
        #pragma unroll
        for (int i = 0; i < 4; i++) {
            int cb = (i * 4 + wave) * 64;           // wave-uniform chunk base
            int ch = cb + lane;
            int row = ch >> 3;
            int c8 = (ch & 7) ^ (row & 7);          // inverse swizzle on source
            gload_lds16(At + (size_t)row * 512 + c8 * 8, (char*)As[b] + cb * 16);
            gload_lds16(Bt2 + (size_t)row * 512 + c8 * 8, (char*)Bs[b] + cb * 16);
        }
    };

    stage(0, 0);
    __syncthreads();
    #pragma unroll
    for (int t = 0; t < 8; t++) {
        const int cur = t & 1;
        if (t < 7) stage(t + 1, cur ^ 1);            // prefetch next tile
        #pragma unroll
        for (int kk = 0; kk < 64; kk += 32) {
            short8 af[4], bfr[4];
            #pragma unroll
            for (int m = 0; m < 4; m++) {
                int row = wm + m * 16 + r;
                int boff = (row * 128 + (kk + kq) * 2) ^ ((row & 7) << 4);
                af[m] = *(const short8*)((const char*)As[cur] + boff);
            }
            #pragma unroll
            for (int n = 0; n < 4; n++) {
                int row = wn + n * 16 + r;
                int boff = (row * 128 + (kk + kq) * 2) ^ ((row & 7) << 4);
                bfr[n] = *(const short8*)((const char*)Bs[cur] + boff);
            }
            #pragma unroll
            for (int m = 0; m < 4; m++)
                #pragma unroll
                for (int n = 0; n < 4; n++)
                    acc[m][n] = __builtin_amdgcn_mfma_f32_16x16x32_bf16(
                        af[m], bfr[n], acc[m][n], 0, 0, 0);
        }
        __syncthreads();
    }
    const int r4 = (lane >> 4) * 4;
    const int cc = lane & 15;
    #pragma unroll
    for (int m = 0; m < 4; m++) {
        #pragma unroll
        for (int n = 0; n < 4; n++) {
            int cg = n0 + wn + n * 16 + cc;
            float bias = (cg < 512) ? b0[cg] : (cg < 1024) ? b1[cg - 512] : b2[cg - 1024];
            #pragma unroll
            for (int i = 0; i < 4; i++) {
                int rg = m0 + wm + m * 16 + r4 + i;
                obf[(size_t)rg * 1536 + cg] = f2bf(acc[m][n][i] + bias);
            }
        }
    }
}

// ---------------- fused attention + proj + bias + residual + LN ------------
// Per block: 64 rows, 512 threads = 8 waves, LDS 66 KB -> 2 blocks/CU.
// Phase 1: head-axis attention -> As as 8 subtiles [kc][64r][64c], each with
//          stride-128B rows + XOR swizzle (the proven 0-conflict layout).
// Phase 2: GEMM vs woT: A from LDS, B DIRECT from global (woT is 512 KB,
//          L2-resident; each bfr load = 16 rows x 64B cache lines).
//          Wave tile 32 rows x 128 cols (2Mw x 4Nw).
// Phase 3: bias + residual + LayerNorm epilogue -> xrow (bf16).
__global__ __launch_bounds__(512, 4) void attn_proj_ln_kernel(
    const ushort* __restrict__ qkv, const ushort* __restrict__ Bt,
    const float* __restrict__ bo_, const float* __restrict__ gw,
    const float* __restrict__ bw, ushort* __restrict__ xrow) {
    __shared__ alignas(16) ushort As[8][64 * 64];   // 64 KB
    __shared__ float ps[4][64], pss[4][64];         //  2 KB
    const int tid = threadIdx.x;
    const int lane = tid & 63;
    const int wave = tid >> 6;            // 0..7
    const int m0 = blockIdx.x * 64;

    // ---- phase 1: attention, 8 rows per wave ----
    {
        const int h = lane >> 3, g = lane & 7;
        for (int it = 0; it < 8; it++) {
            int lrow = wave * 8 + it;
            const ushort* base = qkv + (size_t)(m0 + lrow) * 1536;
            const ushort* qp = base + h * 64;
            const ushort* kp = base + 512 + g * 64;
            float s = 0.f;
            #pragma unroll
            for (int dc = 0; dc < 8; dc++) {
                short8 q8 = *(const short8*)(qp + dc * 8);
                short8 k8 = *(const short8*)(kp + dc * 8);
                #pragma unroll
                for (int j = 0; j < 8; j++) s += bf2f((ushort)q8[j]) * bf2f((ushort)k8[j]);
            }
            s *= 0.125f;  // 1/sqrt(64)
            float mx = s;
            #pragma unroll
            for (int o = 1; o < 8; o <<= 1) mx = fmaxf(mx, __shfl_xor(mx, o));
            float e = __expf(s - mx);
            float den = e;
            #pragma unroll
            for (int o = 1; o < 8; o <<= 1) den += __shfl_xor(den, o);
            float att = e / den;
            float o8[8];
            #pragma unroll
            for (int j = 0; j < 8; j++) o8[j] = 0.f;
            const ushort* vp = base + 1024 + (lane & 7) * 8;
            #pragma unroll
            for (int gg = 0; gg < 8; gg++) {
                float a = __shfl(att, (lane & 56) | gg);
                short8 v8 = *(const short8*)(vp + gg * 64);
                #pragma unroll
                for (int j = 0; j < 8; j++) o8[j] += a * bf2f((ushort)v8[j]);
            }
            short8 ov;
            #pragma unroll
            for (int j = 0; j < 8; j++) ov[j] = (short)f2bf(o8[j]);
            // hid col c = lane*8+j -> subtile kc=lane>>3, col-in-tile=(lane&7)*8+j
            int off = (lrow * 128 + (lane & 7) * 16) ^ ((lrow & 7) << 4);
            *(short8*)((char*)As[lane >> 3] + off) = ov;
        }
    }
    __syncthreads();

    // ---- phase 2: GEMM 32x128 per wave; B direct from global ----
    const int r = lane & 15;
    const int kq = (lane >> 4) * 8;
    const int wrow = (wave >> 2) * 32;    // 0 | 32
    const int wcol = (wave & 3) * 128;    // 0..384
    f32x4 acc[2][8] = {};
    for (int kc = 0; kc < 8; kc++) {
        #pragma unroll
        for (int kk = 0; kk < 64; kk += 32) {
            short8 af[2];
            #pragma unroll
            for (int m = 0; m < 2; m++) {
                int row = wrow + m * 16 + r;
                int boff = (row * 128 + (kk + kq) * 2) ^ ((row & 7) << 4);
                af[m] = *(const short8*)((const char*)As[kc] + boff);
            }
            #pragma unroll
            for (int n = 0; n < 8; n++) {
                int gcol = wcol + n * 16 + r;
                short8 bfr = *(const short8*)(Bt + (size_t)gcol * 512 + kc * 64 + kk + kq);
                acc[0][n] = __builtin_amdgcn_mfma_f32_16x16x32_bf16(
                    af[0], bfr, acc[0][n], 0, 0, 0);
                acc[1][n] = __builtin_amdgcn_mfma_f32_16x16x32_bf16(
                    af[1], bfr, acc[1][n], 0, 0, 0);
            }
        }
    }

    // ---- phase 3: bias + residual, row stats, LN, bf16 store ----
    const int r4 = (lane >> 4) * 4;
    const int cc = lane & 15;
    float gv[8], bv8[8], bov[8];
    #pragma unroll
    for (int n = 0; n < 8; n++) {
        int col = wcol + n * 16 + cc;
        gv[n] = gw[col]; bv8[n] = bw[col]; bov[n] = bo_[col];
    }
    #pragma unroll
    for (int m = 0; m < 2; m++) {
        #pragma unroll
        for (int i = 0; i < 4; i++) {
            int lrow = wrow + m * 16 + r4 + i;
            float s = 0.f, ss = 0.f;
            #pragma unroll
            for (int n = 0; n < 8; n++) {
                int col = wcol + n * 16 + cc;
                float v = acc[m][n][i] + bov[n]
                        + bf2f(xrow[(size_t)(m0 + lrow) * 512 + col]);
                acc[m][n][i] = v;
                s += v; ss += v * v;
            }
            #pragma unroll
            for (int o = 1; o < 16; o <<= 1) {
                s += __shfl_xor(s, o); ss += __shfl_xor(ss, o);
            }
            if (cc == 0) { ps[wave & 3][lrow] = s; pss[wave & 3][lrow] = ss; }
        }
    }
    __syncthreads();
    #pragma unroll
    for (int m = 0; m < 2; m++) {
        #pragma unroll
        for (int i = 0; i < 4; i++) {
            int lrow = wrow + m * 16 + r4 + i;
            float s  = ps[0][lrow] + ps[1][lrow] + ps[2][lrow] + ps[3][lrow];
            float ss = pss[0][lrow] + pss[1][lrow] + pss[2][lrow] + pss[3][lrow];
            float mean = s * (1.f / 512.f);
            float var = ss * (1.f / 512.f) - mean * mean;
            float rstd = rsqrtf(var + 1e-5f);
            #pragma unroll
            for (int n = 0; n < 8; n++) {
                int col = wcol + n * 16 + cc;
                float y = (acc[m][n][i] - mean) * rstd * gv[n] + bv8[n];
                xrow[(size_t)(m0 + lrow) * 512 + col] = f2bf(y);
            }
        }
    }
}

// ---------------- logits: out = x @ W_lm + b_lm (f32, N=13) ----------------
__global__ __launch_bounds__(256) void logits_kernel(const ushort* __restrict__ x,
                                                     const float* __restrict__ Wlm,
                                                     const float* __restrict__ blm,
                                                     float* __restrict__ out) {
    __shared__ float wl[8 * 64 * 13];   // 26,624 B
    const int tid = threadIdx.x;
    for (int k = tid; k < 512; k += 256) {
        int dst = ((k & 7) * 64 + (k >> 3)) * 13;
        #pragma unroll
        for (int v = 0; v < 13; v++) wl[dst + v] = Wlm[k * 13 + v];
    }
    __syncthreads();
    const int lane = tid & 63;
    const int w = tid >> 6;
    float bl[13];
    #pragma unroll
    for (int v = 0; v < 13; v++) bl[v] = blm[v];
    for (int it = 0; it < 8; it++) {
        size_t row = (size_t)blockIdx.x * 32 + it * 4 + w;
        short8 xv = *(const short8*)(x + row * 512 + lane * 8);
        float p[13];
        #pragma unroll
        for (int v = 0; v < 13; v++) p[v] = 0.f;
        #pragma unroll
        for (int j = 0; j < 8; j++) {
            float xf = bf2f((ushort)xv[j]);
            const float* wr = wl + (j * 64 + lane) * 13;
            #pragma unroll
            for (int v = 0; v < 13; v++) p[v] += xf * wr[v];
        }
        #pragma unroll
        for (int v = 0; v < 13; v++) {
            #pragma unroll
            for (int o = 32; o > 0; o >>= 1) p[v] += __shfl_xor(p[v], o);
        }
        if (lane == 0) {
            #pragma unroll
            for (int v = 0; v < 13; v++) out[row * 13 + v] = p[v] + bl[v];
        }
    }
}

// ---------------- loss over (b, t=127) rows --------------------------------
__global__ void loss_kernel(const float* __restrict__ logits,
                            const int* __restrict__ label, float* __restrict__ out) {
    const int tid = threadIdx.x;
    float acc = 0.f;
    for (int b = tid; b < 512; b += 256) {
        const float* lg = logits + ((size_t)b * 128 + 127) * 13;
        float mx = lg[0];
        #pragma unroll
        for (int v = 1; v < 13; v++) mx = fmaxf(mx, lg[v]);
        float den = 0.f;
        #pragma unroll
        for (int v = 0; v < 13; v++) den += expf(lg[v] - mx);
        int lab = label[b];
        acc += -(lg[lab] - mx - logf(den));
    }
    #pragma unroll
    for (int o = 32; o > 0; o >>= 1) acc += __shfl_xor(acc, o);
    __shared__ float red[4];
    if ((tid & 63) == 0) red[tid >> 6] = acc;
    __syncthreads();
    if (tid == 0) out[0] = (red[0] + red[1] + red[2] + red[3]) * (1.f / 512.f);
}

// ---------------------------------------------------------------------------
extern "C" void kernel_launch(void* const* d_in, const int* in_sizes, int n_in,
                              void* d_out, int out_size, void* d_ws, size_t ws_size,
                              hipStream_t stream) {
    const int*   tok   = (const int*)d_in[0];
    const int*   label = (const int*)d_in[1];
    const float* wte   = (const float*)d_in[2];
    const float* wpe   = (const float*)d_in[3];
    const float* Wq    = (const float*)d_in[4];
    const float* bq    = (const float*)d_in[5];
    const float* Wk    = (const float*)d_in[6];
    const float* bk    = (const float*)d_in[7];
    const float* Wv    = (const float*)d_in[8];
    const float* bv    = (const float*)d_in[9];
    const float* Wo    = (const float*)d_in[10];
    const float* bo    = (const float*)d_in[11];
    const float* ln_g  = (const float*)d_in[12];
    const float* ln_b  = (const float*)d_in[13];
    const float* Wlm   = (const float*)d_in[14];
    const float* blm   = (const float*)d_in[15];
    float* out = (float*)d_out;

    char* ws = (char*)d_ws;
    ushort* xbf   = (ushort*)(ws);                 // 67,108,864 B
    ushort* wqkvT = (ushort*)(ws + 67108864);      //  9,437,184 B
    ushort* woT   = (ushort*)(ws + 76546048);      //  3,145,728 B
    const size_t off_dyn = 79691776;

    // chunk rows R: qkv_c 3072 B/row
    int R = 65536;
    while (R > 1024 && off_dyn + (size_t)R * 3072 > ws_size) R >>= 1;
    const int nchunk = 65536 / R;
    ushort* qkv_c = (ushort*)(ws + off_dyn);

    prep_weights<<<24576, 256, 0, stream>>>(Wq, Wk, Wv, Wo, wqkvT, woT);
    embed_kernel<<<16384, 256, 0, stream>>>(tok, wte, wpe, xbf);

    const int nm = R / 128;                        // m-blocks (multiple of 8)
    for (int l = 0; l < 6; l++) {
        for (int c = 0; c < nchunk; c++) {
            const size_t base = (size_t)c * R;
            gemm_qkv_kernel<<<nm * 12, 256, 0, stream>>>(
                xbf + base * 512, wqkvT + (size_t)l * 1536 * 512, nm,
                bq + l * 512, bk + l * 512, bv + l * 512, qkv_c);
            attn_proj_ln_kernel<<<R / 64, 512, 0, stream>>>(
                qkv_c, woT + (size_t)l * 512 * 512, bo + l * 512,
                ln_g + l * 512, ln_b + l * 512, xbf + base * 512);
        }
    }

    logits_kernel<<<2048, 256, 0, stream>>>(xbf, Wlm, blm, out);
    loss_kernel<<<1, 256, 0, stream>>>(out, label, out + 851968);
}

// Round 8
// 382.258 us; speedup vs baseline: 6.4697x; 6.4697x over previous
//
#include <hip/hip_runtime.h>
#include <hip/hip_bf16.h>
#include <cstdint>
#include <cstddef>

// ---------------------------------------------------------------------------
// Transformer_78941498901000 — round 7: DEDUP. Attention mixes only the head
// axis at each (b,t) => every row of the forward pass depends only on
// (token_id, position). Compute the net for the 13*128 = 1664 unique rows,
// then gather logits[b,t] = lu[tok[b,t], t].
// B=512 T=128 C=512 H=8 D=64 L=6 V=13, BT=65536, U = V*T = 1664
// d_out = logits f32 [851968] ++ loss f32 [1]
//
// ws layout (bytes), ~21.2 MB total:
//   xbf   @ 0          : bf16 [1664,512]      1,703,936   (residual stream)
//   wqkvT @ 1,703,936  : bf16 [L][1536][512]  9,437,184   (n-major, k-minor)
//   woT   @ 11,141,120 : bf16 [L][512][512]   3,145,728
//   qkv_u @ 14,286,848 : bf16 [1664,1536]     5,111,808
//   hid_u @ 19,398,656 : bf16 [1664,512]      1,703,936
//   lu    @ 21,102,592 : f32  [1664,13]          86,528
// ---------------------------------------------------------------------------

typedef __attribute__((ext_vector_type(8))) short short8;
typedef __attribute__((ext_vector_type(4))) float f32x4;

__device__ __forceinline__ float bf2f(ushort u) {
    return __uint_as_float(((unsigned int)u) << 16);
}
__device__ __forceinline__ ushort f2bf(float f) {
    unsigned int x = __float_as_uint(f);
    unsigned int r = (x + 0x7fffu + ((x >> 16) & 1u)) >> 16;  // RNE
    return (ushort)r;
}
// async global->LDS, 16B per lane; dst must be wave-uniform base (lane*16 HW)
__device__ __forceinline__ void gload_lds16(const void* g, void* l) {
    __builtin_amdgcn_global_load_lds(
        (const __attribute__((address_space(1))) void*)g,
        (__attribute__((address_space(3))) void*)l, 16, 0, 0);
}

// ---------------- weight prep: coalesced LDS transpose ---------------------
// 24 matrices (6L x {q,k,v,o}) of 512x512 f32 (k-major) -> bf16 (n-major).
// Block = one 64x64 tile; 8x8 tiles per matrix; grid 24*64 = 1536.
__global__ __launch_bounds__(256) void prep_weights(
    const float* __restrict__ Wq, const float* __restrict__ Wk,
    const float* __restrict__ Wv, const float* __restrict__ Wo,
    ushort* __restrict__ wqkvT, ushort* __restrict__ woT) {
    __shared__ float lds[64][65];
    const int bid = blockIdx.x;
    const int mat = bid >> 6;           // 0..23
    const int tile = bid & 63;
    const int tr = tile >> 3, tc = tile & 7;
    const int l = mat >> 2, which = mat & 3;
    const float* S;
    switch (which) {
        case 0: S = Wq; break;
        case 1: S = Wk; break;
        case 2: S = Wv; break;
        default: S = Wo; break;
    }
    S += (size_t)l * 262144;
    ushort* T = (which < 3) ? wqkvT + (size_t)l * 786432 + which * 262144
                            : woT + (size_t)l * 262144;
    const int tid = threadIdx.x;
    const int c = tid & 63;
    #pragma unroll
    for (int it = 0; it < 16; it++) {
        int r = it * 4 + (tid >> 6);
        lds[r][c] = S[(size_t)(tr * 64 + r) * 512 + tc * 64 + c];
    }
    __syncthreads();
    #pragma unroll
    for (int it = 0; it < 16; it++) {
        int r = it * 4 + (tid >> 6);
        T[(size_t)(tc * 64 + r) * 512 + tr * 64 + c] = f2bf(lds[c][r]);
    }
}

// ---------------- unique-row table: xu[v*128+t] = wte[v] + wpe[t] ----------
__global__ __launch_bounds__(256) void build_xu(const float* __restrict__ wte,
                                                const float* __restrict__ wpe,
                                                ushort* __restrict__ xbf) {
    size_t idx = (size_t)blockIdx.x * 256 + threadIdx.x;  // one short8 per thread
    size_t u = idx >> 6;                // 64 chunks of 8 per row; u < 1664
    int c8 = (int)(idx & 63);
    int v = (int)(u >> 7);
    int t = (int)(u & 127);
    const float* ep = wte + (size_t)v * 512 + c8 * 8;
    const float* pp = wpe + (size_t)t * 512 + c8 * 8;
    float4 e0 = *(const float4*)ep, e1 = *(const float4*)(ep + 4);
    float4 p0 = *(const float4*)pp, p1 = *(const float4*)(pp + 4);
    float s[8] = {e0.x + p0.x, e0.y + p0.y, e0.z + p0.z, e0.w + p0.w,
                  e1.x + p1.x, e1.y + p1.y, e1.z + p1.z, e1.w + p1.w};
    short8 o;
    #pragma unroll
    for (int j = 0; j < 8; j++) o[j] = (short)f2bf(s[j]);
    *(short8*)(xbf + u * 512 + c8 * 8) = o;
}

// ---------------- QKV GEMM: qkv = A[1664,512] @ Bt[1536,512]^T + bias ------
// 128x128 tile, BK=64, 4 waves, double-buffered global_load_lds (proven r5).
__global__ __launch_bounds__(256) void gemm_qkv_kernel(
    const ushort* __restrict__ A, const ushort* __restrict__ Bt,
    const float* __restrict__ b0, const float* __restrict__ b1,
    const float* __restrict__ b2, ushort* __restrict__ obf) {
    __shared__ alignas(16) ushort As[2][128 * 64];   // 2 x 16 KB
    __shared__ alignas(16) ushort Bs[2][128 * 64];   // 2 x 16 KB
    const int tid = threadIdx.x;
    const int lane = tid & 63;
    const int wave = tid >> 6;
    const int m0 = blockIdx.x * 128;
    const int n0 = blockIdx.y * 128;
    const int wm = (wave >> 1) * 64;
    const int wn = (wave & 1) * 64;
    const int r = lane & 15;
    const int kq = (lane >> 4) * 8;
    const ushort* Ab = A  + (size_t)m0 * 512;
    const ushort* Bb = Bt + (size_t)n0 * 512;
    f32x4 acc[4][4] = {};

    auto stage = [&](int t, int b) {
        const ushort* At = Ab + t * 64;
        const ushort* Bt2 = Bb + t * 64;
        #pragma unroll
        for (int i = 0; i < 4; i++) {
            int cb = (i * 4 + wave) * 64;           // wave-uniform chunk base
            int ch = cb + lane;
            int row = ch >> 3;
            int c8 = (ch & 7) ^ (row & 7);          // inverse swizzle on source
            gload_lds16(At + (size_t)row * 512 + c8 * 8, (char*)As[b] + cb * 16);
            gload_lds16(Bt2 + (size_t)row * 512 + c8 * 8, (char*)Bs[b] + cb * 16);
        }
    };

    stage(0, 0);
    __syncthreads();
    #pragma unroll
    for (int t = 0; t < 8; t++) {
        const int cur = t & 1;
        if (t < 7) stage(t + 1, cur ^ 1);            // prefetch next tile
        #pragma unroll
        for (int kk = 0; kk < 64; kk += 32) {
            short8 af[4], bfr[4];
            #pragma unroll
            for (int m = 0; m < 4; m++) {
                int row = wm + m * 16 + r;
                int boff = (row * 128 + (kk + kq) * 2) ^ ((row & 7) << 4);
                af[m] = *(const short8*)((const char*)As[cur] + boff);
            }
            #pragma unroll
            for (int n = 0; n < 4; n++) {
                int row = wn + n * 16 + r;
                int boff = (row * 128 + (kk + kq) * 2) ^ ((row & 7) << 4);
                bfr[n] = *(const short8*)((const char*)Bs[cur] + boff);
            }
            #pragma unroll
            for (int m = 0; m < 4; m++)
                #pragma unroll
                for (int n = 0; n < 4; n++)
                    acc[m][n] = __builtin_amdgcn_mfma_f32_16x16x32_bf16(
                        af[m], bfr[n], acc[m][n], 0, 0, 0);
        }
        __syncthreads();
    }
    const int r4 = (lane >> 4) * 4;
    const int cc = lane & 15;
    #pragma unroll
    for (int m = 0; m < 4; m++) {
        #pragma unroll
        for (int n = 0; n < 4; n++) {
            int cg = n0 + wn + n * 16 + cc;
            float bias = (cg < 512) ? b0[cg] : (cg < 1024) ? b1[cg - 512] : b2[cg - 1024];
            #pragma unroll
            for (int i = 0; i < 4; i++) {
                int rg = m0 + wm + m * 16 + r4 + i;
                obf[(size_t)rg * 1536 + cg] = f2bf(acc[m][n][i] + bias);
            }
        }
    }
}

// ---------------- per-position head-axis attention -------------------------
__global__ __launch_bounds__(256) void attn_kernel(const ushort* __restrict__ qkv,
                                                   ushort* __restrict__ hid) {
    const int lane = threadIdx.x & 63;
    const size_t pos = (size_t)blockIdx.x * 4 + (threadIdx.x >> 6);
    const ushort* base = qkv + pos * 1536;
    const int h = lane >> 3, g = lane & 7;
    const ushort* qp = base + h * 64;
    const ushort* kp = base + 512 + g * 64;
    float s = 0.f;
    #pragma unroll
    for (int dc = 0; dc < 8; dc++) {
        short8 q8 = *(const short8*)(qp + dc * 8);
        short8 k8 = *(const short8*)(kp + dc * 8);
        #pragma unroll
        for (int j = 0; j < 8; j++) s += bf2f((ushort)q8[j]) * bf2f((ushort)k8[j]);
    }
    s *= 0.125f;  // 1/sqrt(64)
    float mx = s;
    #pragma unroll
    for (int o = 1; o < 8; o <<= 1) mx = fmaxf(mx, __shfl_xor(mx, o));
    float e = __expf(s - mx);
    float den = e;
    #pragma unroll
    for (int o = 1; o < 8; o <<= 1) den += __shfl_xor(den, o);
    float att = e / den;
    float o8[8];
    #pragma unroll
    for (int j = 0; j < 8; j++) o8[j] = 0.f;
    const ushort* vp = base + 1024 + (lane & 7) * 8;
    #pragma unroll
    for (int gg = 0; gg < 8; gg++) {
        float a = __shfl(att, (lane & 56) | gg);
        short8 v8 = *(const short8*)(vp + gg * 64);
        #pragma unroll
        for (int j = 0; j < 8; j++) o8[j] += a * bf2f((ushort)v8[j]);
    }
    short8 ov;
    #pragma unroll
    for (int j = 0; j < 8; j++) ov[j] = (short)f2bf(o8[j]);
    *(short8*)(hid + pos * 512 + lane * 8) = ov;
}

// ---------------- fused proj + bias + residual + LayerNorm -----------------
// BM=128, BN=512 (full row), BK=64, 1024 threads = 16 waves (2M x 8N). r5 ver.
__global__ __launch_bounds__(1024) void proj_ln_kernel(
    const ushort* __restrict__ A, const ushort* __restrict__ Bt,
    const float* __restrict__ bo_, const float* __restrict__ gw,
    const float* __restrict__ bw, ushort* __restrict__ xrow) {
    __shared__ alignas(16) ushort As[128 * 64];   // 16 KB
    __shared__ alignas(16) ushort Bs[512 * 64];   // 64 KB
    __shared__ float ps[8][128], pss[8][128];     //  8 KB
    const int tid = threadIdx.x;
    const int lane = tid & 63;
    const int wave = tid >> 6;            // 0..15
    const int m0 = blockIdx.x * 128;
    const int wm = (wave >> 3) * 64;      // 0 | 64
    const int wn = (wave & 7) * 64;       // 0..448
    const int r = lane & 15;
    const int kq = (lane >> 4) * 8;
    f32x4 acc[4][4] = {};

    for (int k0 = 0; k0 < 512; k0 += 64) {
        const ushort* Ab = A  + (size_t)m0 * 512 + k0;
        const ushort* Bb = Bt + k0;
        {   // stage A: 1024 chunks, one per lane across 16 waves
            int cb = wave * 64, ch = cb + lane;
            int row = ch >> 3;
            int c8 = (ch & 7) ^ (row & 7);
            gload_lds16(Ab + (size_t)row * 512 + c8 * 8, (char*)As + cb * 16);
        }
        #pragma unroll
        for (int i = 0; i < 4; i++) {   // stage B: 4096 chunks
            int cb = (i * 16 + wave) * 64, ch = cb + lane;
            int brow = ch >> 3;
            int c8 = (ch & 7) ^ (brow & 7);
            gload_lds16(Bb + (size_t)brow * 512 + c8 * 8, (char*)Bs + cb * 16);
        }
        __syncthreads();
        #pragma unroll
        for (int kk = 0; kk < 64; kk += 32) {
            short8 af[4], bfr[4];
            #pragma unroll
            for (int m = 0; m < 4; m++) {
                int row = wm + m * 16 + r;
                int boff = (row * 128 + (kk + kq) * 2) ^ ((row & 7) << 4);
                af[m] = *(const short8*)((const char*)As + boff);
            }
            #pragma unroll
            for (int n = 0; n < 4; n++) {
                int row = wn + n * 16 + r;
                int boff = (row * 128 + (kk + kq) * 2) ^ ((row & 7) << 4);
                bfr[n] = *(const short8*)((const char*)Bs + boff);
            }
            #pragma unroll
            for (int m = 0; m < 4; m++)
                #pragma unroll
                for (int n = 0; n < 4; n++)
                    acc[m][n] = __builtin_amdgcn_mfma_f32_16x16x32_bf16(
                        af[m], bfr[n], acc[m][n], 0, 0, 0);
        }
        __syncthreads();
    }

    const int r4 = (lane >> 4) * 4;
    const int cc = lane & 15;
    float gv[4], bv4[4], bov[4];
    #pragma unroll
    for (int n = 0; n < 4; n++) {
        int col = wn + n * 16 + cc;
        gv[n] = gw[col]; bv4[n] = bw[col]; bov[n] = bo_[col];
    }
    #pragma unroll
    for (int m = 0; m < 4; m++) {
        #pragma unroll
        for (int i = 0; i < 4; i++) {
            int lrow = wm + m * 16 + r4 + i;
            float s = 0.f, ss = 0.f;
            #pragma unroll
            for (int n = 0; n < 4; n++) {
                int col = wn + n * 16 + cc;
                float v = acc[m][n][i] + bov[n]
                        + bf2f(xrow[(size_t)(m0 + lrow) * 512 + col]);
                acc[m][n][i] = v;
                s += v; ss += v * v;
            }
            #pragma unroll
            for (int o = 1; o < 16; o <<= 1) {
                s += __shfl_xor(s, o); ss += __shfl_xor(ss, o);
            }
            if (cc == 0) { ps[wave & 7][lrow] = s; pss[wave & 7][lrow] = ss; }
        }
    }
    __syncthreads();
    #pragma unroll
    for (int m = 0; m < 4; m++) {
        #pragma unroll
        for (int i = 0; i < 4; i++) {
            int lrow = wm + m * 16 + r4 + i;
            float s = 0.f, ss = 0.f;
            #pragma unroll
            for (int w = 0; w < 8; w++) { s += ps[w][lrow]; ss += pss[w][lrow]; }
            float mean = s * (1.f / 512.f);
            float var = ss * (1.f / 512.f) - mean * mean;
            float rstd = rsqrtf(var + 1e-5f);
            #pragma unroll
            for (int n = 0; n < 4; n++) {
                int col = wn + n * 16 + cc;
                float y = (acc[m][n][i] - mean) * rstd * gv[n] + bv4[n];
                xrow[(size_t)(m0 + lrow) * 512 + col] = f2bf(y);
            }
        }
    }
}

// ---------------- logits_u: lu = xu @ W_lm + b_lm (f32, N=13) --------------
__global__ __launch_bounds__(256) void logits_kernel(const ushort* __restrict__ x,
                                                     const float* __restrict__ Wlm,
                                                     const float* __restrict__ blm,
                                                     float* __restrict__ lu) {
    __shared__ float wl[8 * 64 * 13];   // 26,624 B
    const int tid = threadIdx.x;
    for (int k = tid; k < 512; k += 256) {
        int dst = ((k & 7) * 64 + (k >> 3)) * 13;
        #pragma unroll
        for (int v = 0; v < 13; v++) wl[dst + v] = Wlm[k * 13 + v];
    }
    __syncthreads();
    const int lane = tid & 63;
    const int w = tid >> 6;
    float bl[13];
    #pragma unroll
    for (int v = 0; v < 13; v++) bl[v] = blm[v];
    for (int it = 0; it < 8; it++) {
        size_t row = (size_t)blockIdx.x * 32 + it * 4 + w;   // < 1664
        short8 xv = *(const short8*)(x + row * 512 + lane * 8);
        float p[13];
        #pragma unroll
        for (int v = 0; v < 13; v++) p[v] = 0.f;
        #pragma unroll
        for (int j = 0; j < 8; j++) {
            float xf = bf2f((ushort)xv[j]);
            const float* wr = wl + (j * 64 + lane) * 13;
            #pragma unroll
            for (int v = 0; v < 13; v++) p[v] += xf * wr[v];
        }
        #pragma unroll
        for (int v = 0; v < 13; v++) {
            #pragma unroll
            for (int o = 32; o > 0; o >>= 1) p[v] += __shfl_xor(p[v], o);
        }
        if (lane == 0) {
            #pragma unroll
            for (int v = 0; v < 13; v++) lu[row * 13 + v] = p[v] + bl[v];
        }
    }
}

// ---------------- scatter: out[b,t,:] = lu[tok[b,t]*128 + t, :] ------------
__global__ __launch_bounds__(256) void scatter_kernel(const float* __restrict__ lu,
                                                      const int* __restrict__ tok,
                                                      float* __restrict__ out) {
    unsigned int i = blockIdx.x * 256 + threadIdx.x;   // < 851968 exactly
    unsigned int bt = i / 13u;
    unsigned int vv = i - bt * 13u;
    int v = tok[bt];
    int t = (int)(bt & 127u);
    out[i] = lu[(size_t)((v << 7) + t) * 13 + vv];
}

// ---------------- loss over (b, t=127) rows --------------------------------
__global__ void loss_kernel(const float* __restrict__ lu,
                            const int* __restrict__ tok,
                            const int* __restrict__ label,
                            float* __restrict__ out) {
    const int tid = threadIdx.x;
    float acc = 0.f;
    for (int b = tid; b < 512; b += 256) {
        int v = tok[b * 128 + 127];
        const float* lg = lu + (size_t)((v << 7) + 127) * 13;
        float mx = lg[0];
        #pragma unroll
        for (int vv = 1; vv < 13; vv++) mx = fmaxf(mx, lg[vv]);
        float den = 0.f;
        #pragma unroll
        for (int vv = 0; vv < 13; vv++) den += expf(lg[vv] - mx);
        int lab = label[b];
        acc += -(lg[lab] - mx - logf(den));
    }
    #pragma unroll
    for (int o = 32; o > 0; o >>= 1) acc += __shfl_xor(acc, o);
    __shared__ float red[4];
    if ((tid & 63) == 0) red[tid >> 6] = acc;
    __syncthreads();
    if (tid == 0) out[0] = (red[0] + red[1] + red[2] + red[3]) * (1.f / 512.f);
}

// ---------------------------------------------------------------------------
extern "C" void kernel_launch(void* const* d_in, const int* in_sizes, int n_in,
                              void* d_out, int out_size, void* d_ws, size_t ws_size,
                              hipStream_t stream) {
    const int*   tok   = (const int*)d_in[0];
    const int*   label = (const int*)d_in[1];
    const float* wte   = (const float*)d_in[2];
    const float* wpe   = (const float*)d_in[3];
    const float* Wq    = (const float*)d_in[4];
    const float* bq    = (const float*)d_in[5];
    const float* Wk    = (const float*)d_in[6];
    const float* bk    = (const float*)d_in[7];
    const float* Wv    = (const float*)d_in[8];
    const float* bv    = (const float*)d_in[9];
    const float* Wo    = (const float*)d_in[10];
    const float* bo    = (const float*)d_in[11];
    const float* ln_g  = (const float*)d_in[12];
    const float* ln_b  = (const float*)d_in[13];
    const float* Wlm   = (const float*)d_in[14];
    const float* blm   = (const float*)d_in[15];
    float* out = (float*)d_out;

    char* ws = (char*)d_ws;
    ushort* xbf   = (ushort*)(ws);                 // 1,703,936 B
    ushort* wqkvT = (ushort*)(ws + 1703936);       // 9,437,184 B
    ushort* woT   = (ushort*)(ws + 11141120);      // 3,145,728 B
    ushort* qkv_u = (ushort*)(ws + 14286848);      // 5,111,808 B
    ushort* hid_u = (ushort*)(ws + 19398656);      // 1,703,936 B
    float*  lu    = (float*) (ws + 21102592);      //    86,528 B

    prep_weights<<<1536, 256, 0, stream>>>(Wq, Wk, Wv, Wo, wqkvT, woT);
    build_xu<<<416, 256, 0, stream>>>(wte, wpe, xbf);

    for (int l = 0; l < 6; l++) {
        gemm_qkv_kernel<<<dim3(13, 12), 256, 0, stream>>>(
            xbf, wqkvT + (size_t)l * 786432,
            bq + l * 512, bk + l * 512, bv + l * 512, qkv_u);
        attn_kernel<<<416, 256, 0, stream>>>(qkv_u, hid_u);
        proj_ln_kernel<<<13, 1024, 0, stream>>>(
            hid_u, woT + (size_t)l * 262144, bo + l * 512,
            ln_g + l * 512, ln_b + l * 512, xbf);
    }

    logits_kernel<<<52, 256, 0, stream>>>(xbf, Wlm, blm, lu);
    scatter_kernel<<<3328, 256, 0, stream>>>(lu, tok, out);
    loss_kernel<<<1, 256, 0, stream>>>(lu, tok, label, out + 851968);
}

// Round 9
// 228.235 us; speedup vs baseline: 10.8357x; 1.6748x over previous
//
#include <hip/hip_runtime.h>
#include <hip/hip_bf16.h>
#include <cstdint>
#include <cstddef>

// ---------------------------------------------------------------------------
// Transformer_78941498901000 — round 8: latency-tolerant small-M pipeline.
// Dedup (round 7): rows depend only on (token, position) => U = 13*128 = 1664.
// This round: proj split into N-tiled GEMM (grid 208) + LN-finalize; qkv
// re-tiled to BM=64 (grid 312). Everything sized for latency hiding, since
// total FLOP (~21 GF) is trivial — the binding constraint is outstanding-load
// parallelism per dispatch.
// d_out = logits f32 [851968] ++ loss f32 [1]
//
// ws layout (bytes), ~21.3 MB total:
//   xbf   @ 0          : bf16 [1664,512]      1,703,936   (residual stream)
//   wqkvT @ 1,703,936  : bf16 [L][1536][512]  9,437,184   (n-major, k-minor)
//   woT   @ 11,141,120 : bf16 [L][512][512]   3,145,728
//   qkv_u @ 14,286,848 : bf16 [1664,1536]     5,111,808   (alias: tmp bf16 [1664,512])
//   hid_u @ 19,398,656 : bf16 [1664,512]      1,703,936
//   lu    @ 21,102,592 : f32  [1664,13]          86,528
//   ps    @ 21,189,120 : f32  [4][1664]          26,624
//   pss   @ 21,215,744 : f32  [4][1664]          26,624
// ---------------------------------------------------------------------------

typedef __attribute__((ext_vector_type(8))) short short8;
typedef __attribute__((ext_vector_type(4))) float f32x4;

__device__ __forceinline__ float bf2f(ushort u) {
    return __uint_as_float(((unsigned int)u) << 16);
}
__device__ __forceinline__ ushort f2bf(float f) {
    unsigned int x = __float_as_uint(f);
    unsigned int r = (x + 0x7fffu + ((x >> 16) & 1u)) >> 16;  // RNE
    return (ushort)r;
}
// async global->LDS, 16B per lane; dst must be wave-uniform base (lane*16 HW)
__device__ __forceinline__ void gload_lds16(const void* g, void* l) {
    __builtin_amdgcn_global_load_lds(
        (const __attribute__((address_space(1))) void*)g,
        (__attribute__((address_space(3))) void*)l, 16, 0, 0);
}

// ---------------- weight prep: coalesced LDS transpose ---------------------
// 24 matrices (6L x {q,k,v,o}) of 512x512 f32 (k-major) -> bf16 (n-major).
__global__ __launch_bounds__(256) void prep_weights(
    const float* __restrict__ Wq, const float* __restrict__ Wk,
    const float* __restrict__ Wv, const float* __restrict__ Wo,
    ushort* __restrict__ wqkvT, ushort* __restrict__ woT) {
    __shared__ float lds[64][65];
    const int bid = blockIdx.x;
    const int mat = bid >> 6;           // 0..23
    const int tile = bid & 63;
    const int tr = tile >> 3, tc = tile & 7;
    const int l = mat >> 2, which = mat & 3;
    const float* S;
    switch (which) {
        case 0: S = Wq; break;
        case 1: S = Wk; break;
        case 2: S = Wv; break;
        default: S = Wo; break;
    }
    S += (size_t)l * 262144;
    ushort* T = (which < 3) ? wqkvT + (size_t)l * 786432 + which * 262144
                            : woT + (size_t)l * 262144;
    const int tid = threadIdx.x;
    const int c = tid & 63;
    #pragma unroll
    for (int it = 0; it < 16; it++) {
        int r = it * 4 + (tid >> 6);
        lds[r][c] = S[(size_t)(tr * 64 + r) * 512 + tc * 64 + c];
    }
    __syncthreads();
    #pragma unroll
    for (int it = 0; it < 16; it++) {
        int r = it * 4 + (tid >> 6);
        T[(size_t)(tc * 64 + r) * 512 + tr * 64 + c] = f2bf(lds[c][r]);
    }
}

// ---------------- unique-row table: xu[v*128+t] = wte[v] + wpe[t] ----------
__global__ __launch_bounds__(256) void build_xu(const float* __restrict__ wte,
                                                const float* __restrict__ wpe,
                                                ushort* __restrict__ xbf) {
    size_t idx = (size_t)blockIdx.x * 256 + threadIdx.x;  // one short8 per thread
    size_t u = idx >> 6;                // u < 1664
    int c8 = (int)(idx & 63);
    int v = (int)(u >> 7);
    int t = (int)(u & 127);
    const float* ep = wte + (size_t)v * 512 + c8 * 8;
    const float* pp = wpe + (size_t)t * 512 + c8 * 8;
    float4 e0 = *(const float4*)ep, e1 = *(const float4*)(ep + 4);
    float4 p0 = *(const float4*)pp, p1 = *(const float4*)(pp + 4);
    float s[8] = {e0.x + p0.x, e0.y + p0.y, e0.z + p0.z, e0.w + p0.w,
                  e1.x + p1.x, e1.y + p1.y, e1.z + p1.z, e1.w + p1.w};
    short8 o;
    #pragma unroll
    for (int j = 0; j < 8; j++) o[j] = (short)f2bf(s[j]);
    *(short8*)(xbf + u * 512 + c8 * 8) = o;
}

// ---------------- QKV GEMM: qkv = A[1664,512] @ Bt[1536,512]^T + bias ------
// BM=64, BN=128, BK=64, 4 waves (wave tile 32x64), double-buffered
// global_load_lds, XOR-swizzled LDS. grid (26, 12) = 312 blocks.
__global__ __launch_bounds__(256) void gemm_qkv_kernel(
    const ushort* __restrict__ A, const ushort* __restrict__ Bt,
    const float* __restrict__ b0, const float* __restrict__ b1,
    const float* __restrict__ b2, ushort* __restrict__ obf) {
    __shared__ alignas(16) ushort As[2][64 * 64];    // 2 x 8 KB
    __shared__ alignas(16) ushort Bs[2][128 * 64];   // 2 x 16 KB
    const int tid = threadIdx.x;
    const int lane = tid & 63;
    const int wave = tid >> 6;
    const int m0 = blockIdx.x * 64;
    const int n0 = blockIdx.y * 128;
    const int wm = (wave >> 1) * 32;
    const int wn = (wave & 1) * 64;
    const int r = lane & 15;
    const int kq = (lane >> 4) * 8;
    const ushort* Ab = A  + (size_t)m0 * 512;
    const ushort* Bb = Bt + (size_t)n0 * 512;
    f32x4 acc[2][4] = {};

    auto stage = [&](int t, int b) {
        const ushort* At = Ab + t * 64;
        const ushort* Bt2 = Bb + t * 64;
        #pragma unroll
        for (int i = 0; i < 2; i++) {                // A: 512 chunks
            int cb = (i * 4 + wave) * 64;
            int ch = cb + lane;
            int row = ch >> 3;
            int c8 = (ch & 7) ^ (row & 7);
            gload_lds16(At + (size_t)row * 512 + c8 * 8, (char*)As[b] + cb * 16);
        }
        #pragma unroll
        for (int i = 0; i < 4; i++) {                // B: 1024 chunks
            int cb = (i * 4 + wave) * 64;
            int ch = cb + lane;
            int row = ch >> 3;
            int c8 = (ch & 7) ^ (row & 7);
            gload_lds16(Bt2 + (size_t)row * 512 + c8 * 8, (char*)Bs[b] + cb * 16);
        }
    };

    stage(0, 0);
    __syncthreads();
    #pragma unroll
    for (int t = 0; t < 8; t++) {
        const int cur = t & 1;
        if (t < 7) stage(t + 1, cur ^ 1);            // prefetch next tile
        #pragma unroll
        for (int kk = 0; kk < 64; kk += 32) {
            short8 af[2], bfr[4];
            #pragma unroll
            for (int m = 0; m < 2; m++) {
                int row = wm + m * 16 + r;
                int boff = (row * 128 + (kk + kq) * 2) ^ ((row & 7) << 4);
                af[m] = *(const short8*)((const char*)As[cur] + boff);
            }
            #pragma unroll
            for (int n = 0; n < 4; n++) {
                int row = wn + n * 16 + r;
                int boff = (row * 128 + (kk + kq) * 2) ^ ((row & 7) << 4);
                bfr[n] = *(const short8*)((const char*)Bs[cur] + boff);
            }
            #pragma unroll
            for (int m = 0; m < 2; m++)
                #pragma unroll
                for (int n = 0; n < 4; n++)
                    acc[m][n] = __builtin_amdgcn_mfma_f32_16x16x32_bf16(
                        af[m], bfr[n], acc[m][n], 0, 0, 0);
        }
        __syncthreads();
    }
    const int r4 = (lane >> 4) * 4;
    const int cc = lane & 15;
    #pragma unroll
    for (int m = 0; m < 2; m++) {
        #pragma unroll
        for (int n = 0; n < 4; n++) {
            int cg = n0 + wn + n * 16 + cc;
            float bias = (cg < 512) ? b0[cg] : (cg < 1024) ? b1[cg - 512] : b2[cg - 1024];
            #pragma unroll
            for (int i = 0; i < 4; i++) {
                int rg = m0 + wm + m * 16 + r4 + i;
                obf[(size_t)rg * 1536 + cg] = f2bf(acc[m][n][i] + bias);
            }
        }
    }
}

// ---------------- per-position head-axis attention -------------------------
__global__ __launch_bounds__(256) void attn_kernel(const ushort* __restrict__ qkv,
                                                   ushort* __restrict__ hid) {
    const int lane = threadIdx.x & 63;
    const size_t pos = (size_t)blockIdx.x * 4 + (threadIdx.x >> 6);
    const ushort* base = qkv + pos * 1536;
    const int h = lane >> 3, g = lane & 7;
    const ushort* qp = base + h * 64;
    const ushort* kp = base + 512 + g * 64;
    float s = 0.f;
    #pragma unroll
    for (int dc = 0; dc < 8; dc++) {
        short8 q8 = *(const short8*)(qp + dc * 8);
        short8 k8 = *(const short8*)(kp + dc * 8);
        #pragma unroll
        for (int j = 0; j < 8; j++) s += bf2f((ushort)q8[j]) * bf2f((ushort)k8[j]);
    }
    s *= 0.125f;  // 1/sqrt(64)
    float mx = s;
    #pragma unroll
    for (int o = 1; o < 8; o <<= 1) mx = fmaxf(mx, __shfl_xor(mx, o));
    float e = __expf(s - mx);
    float den = e;
    #pragma unroll
    for (int o = 1; o < 8; o <<= 1) den += __shfl_xor(den, o);
    float att = e / den;
    float o8[8];
    #pragma unroll
    for (int j = 0; j < 8; j++) o8[j] = 0.f;
    const ushort* vp = base + 1024 + (lane & 7) * 8;
    #pragma unroll
    for (int gg = 0; gg < 8; gg++) {
        float a = __shfl(att, (lane & 56) | gg);
        short8 v8 = *(const short8*)(vp + gg * 64);
        #pragma unroll
        for (int j = 0; j < 8; j++) o8[j] += a * bf2f((ushort)v8[j]);
    }
    short8 ov;
    #pragma unroll
    for (int j = 0; j < 8; j++) ov[j] = (short)f2bf(o8[j]);
    *(short8*)(hid + pos * 512 + lane * 8) = ov;
}

// ---------------- proj GEMM (N-tiled) + bias + residual + partial stats ----
// tmp[32,128-tile] = A[32,512] @ woT[128,512]^T + bo + xres;  partial sums of
// v and v^2 per row go to ps/pss[nb][row]. grid (52, 4), 256 threads.
__global__ __launch_bounds__(256) void proj_gemm_kernel(
    const ushort* __restrict__ A, const ushort* __restrict__ Bt,
    const float* __restrict__ bo_, const ushort* __restrict__ xres,
    ushort* __restrict__ tmp, float* __restrict__ ps, float* __restrict__ pss) {
    __shared__ alignas(16) ushort As[2][32 * 64];    // 2 x 4 KB
    __shared__ alignas(16) ushort Bs[2][128 * 64];   // 2 x 16 KB
    __shared__ float lps[2][32], lpss[2][32];
    const int tid = threadIdx.x;
    const int lane = tid & 63;
    const int wave = tid >> 6;            // 0..3
    const int m0 = blockIdx.x * 32;
    const int n0 = blockIdx.y * 128;
    const int wm = (wave >> 1) * 16;      // 0 | 16
    const int wn = (wave & 1) * 64;       // 0 | 64
    const int r = lane & 15;
    const int kq = (lane >> 4) * 8;
    const ushort* Ab = A  + (size_t)m0 * 512;
    const ushort* Bb = Bt + (size_t)n0 * 512;
    f32x4 acc[4] = {};

    auto stage = [&](int t, int b) {
        const ushort* At = Ab + t * 64;
        const ushort* Bt2 = Bb + t * 64;
        {                                            // A: 256 chunks, 1/thread
            int cb = wave * 64;
            int ch = cb + lane;
            int row = ch >> 3;
            int c8 = (ch & 7) ^ (row & 7);
            gload_lds16(At + (size_t)row * 512 + c8 * 8, (char*)As[b] + cb * 16);
        }
        #pragma unroll
        for (int i = 0; i < 4; i++) {                // B: 1024 chunks
            int cb = (i * 4 + wave) * 64;
            int ch = cb + lane;
            int row = ch >> 3;
            int c8 = (ch & 7) ^ (row & 7);
            gload_lds16(Bt2 + (size_t)row * 512 + c8 * 8, (char*)Bs[b] + cb * 16);
        }
    };

    stage(0, 0);
    __syncthreads();
    #pragma unroll
    for (int t = 0; t < 8; t++) {
        const int cur = t & 1;
        if (t < 7) stage(t + 1, cur ^ 1);
        #pragma unroll
        for (int kk = 0; kk < 64; kk += 32) {
            int arow = wm + r;
            int aoff = (arow * 128 + (kk + kq) * 2) ^ ((arow & 7) << 4);
            short8 af = *(const short8*)((const char*)As[cur] + aoff);
            #pragma unroll
            for (int n = 0; n < 4; n++) {
                int brow = wn + n * 16 + r;
                int boff = (brow * 128 + (kk + kq) * 2) ^ ((brow & 7) << 4);
                short8 bfr = *(const short8*)((const char*)Bs[cur] + boff);
                acc[n] = __builtin_amdgcn_mfma_f32_16x16x32_bf16(
                    af, bfr, acc[n], 0, 0, 0);
            }
        }
        __syncthreads();
    }

    // epilogue: v = acc + bias + residual; quantize to tmp; per-row partials
    const int r4 = (lane >> 4) * 4;
    const int cc = lane & 15;
    float s_i[4] = {0.f, 0.f, 0.f, 0.f}, ss_i[4] = {0.f, 0.f, 0.f, 0.f};
    #pragma unroll
    for (int n = 0; n < 4; n++) {
        int col = n0 + wn + n * 16 + cc;
        float bias = bo_[col];
        #pragma unroll
        for (int i = 0; i < 4; i++) {
            int rg = m0 + wm + r4 + i;
            float v = acc[n][i] + bias + bf2f(xres[(size_t)rg * 512 + col]);
            tmp[(size_t)rg * 512 + col] = f2bf(v);
            s_i[i] += v; ss_i[i] += v * v;
        }
    }
    #pragma unroll
    for (int i = 0; i < 4; i++) {
        #pragma unroll
        for (int o = 1; o < 16; o <<= 1) {
            s_i[i] += __shfl_xor(s_i[i], o);
            ss_i[i] += __shfl_xor(ss_i[i], o);
        }
    }
    if (cc == 0) {
        #pragma unroll
        for (int i = 0; i < 4; i++) {
            lps[wn >> 6][wm + r4 + i] = s_i[i];
            lpss[wn >> 6][wm + r4 + i] = ss_i[i];
        }
    }
    __syncthreads();
    if (tid < 32) {
        int row = m0 + tid;
        ps[blockIdx.y * 1664 + row]  = lps[0][tid] + lps[1][tid];
        pss[blockIdx.y * 1664 + row] = lpss[0][tid] + lpss[1][tid];
    }
}

// ---------------- LN finalize: xbf = bf16(LN(tmp)) -------------------------
__global__ __launch_bounds__(256) void ln_finalize_kernel(
    const ushort* __restrict__ tmp, const float* __restrict__ ps,
    const float* __restrict__ pss, const float* __restrict__ gw,
    const float* __restrict__ bw, ushort* __restrict__ xbf) {
    const int lane = threadIdx.x & 63;
    const size_t row = (size_t)blockIdx.x * 4 + (threadIdx.x >> 6);
    float s  = ps[row]  + ps[1664 + row]  + ps[2 * 1664 + row]  + ps[3 * 1664 + row];
    float ss = pss[row] + pss[1664 + row] + pss[2 * 1664 + row] + pss[3 * 1664 + row];
    float mean = s * (1.f / 512.f);
    float var = ss * (1.f / 512.f) - mean * mean;
    float rstd = rsqrtf(var + 1e-5f);
    short8 tv = *(const short8*)(tmp + row * 512 + lane * 8);
    const float* gp = gw + lane * 8;
    const float* bp = bw + lane * 8;
    float4 g0 = *(const float4*)gp, g1 = *(const float4*)(gp + 4);
    float4 b0 = *(const float4*)bp, b1 = *(const float4*)(bp + 4);
    float gg[8] = {g0.x, g0.y, g0.z, g0.w, g1.x, g1.y, g1.z, g1.w};
    float bb[8] = {b0.x, b0.y, b0.z, b0.w, b1.x, b1.y, b1.z, b1.w};
    short8 o;
    #pragma unroll
    for (int j = 0; j < 8; j++)
        o[j] = (short)f2bf((bf2f((ushort)tv[j]) - mean) * rstd * gg[j] + bb[j]);
    *(short8*)(xbf + row * 512 + lane * 8) = o;
}

// ---------------- logits_u: lu = xu @ W_lm + b_lm (f32, N=13) --------------
__global__ __launch_bounds__(256) void logits_kernel(const ushort* __restrict__ x,
                                                     const float* __restrict__ Wlm,
                                                     const float* __restrict__ blm,
                                                     float* __restrict__ lu) {
    __shared__ float wl[8 * 64 * 13];   // 26,624 B
    const int tid = threadIdx.x;
    for (int k = tid; k < 512; k += 256) {
        int dst = ((k & 7) * 64 + (k >> 3)) * 13;
        #pragma unroll
        for (int v = 0; v < 13; v++) wl[dst + v] = Wlm[k * 13 + v];
    }
    __syncthreads();
    const int lane = tid & 63;
    const int w = tid >> 6;
    float bl[13];
    #pragma unroll
    for (int v = 0; v < 13; v++) bl[v] = blm[v];
    for (int it = 0; it < 8; it++) {
        size_t row = (size_t)blockIdx.x * 32 + it * 4 + w;   // < 1664
        short8 xv = *(const short8*)(x + row * 512 + lane * 8);
        float p[13];
        #pragma unroll
        for (int v = 0; v < 13; v++) p[v] = 0.f;
        #pragma unroll
        for (int j = 0; j < 8; j++) {
            float xf = bf2f((ushort)xv[j]);
            const float* wr = wl + (j * 64 + lane) * 13;
            #pragma unroll
            for (int v = 0; v < 13; v++) p[v] += xf * wr[v];
        }
        #pragma unroll
        for (int v = 0; v < 13; v++) {
            #pragma unroll
            for (int o = 32; o > 0; o >>= 1) p[v] += __shfl_xor(p[v], o);
        }
        if (lane == 0) {
            #pragma unroll
            for (int v = 0; v < 13; v++) lu[row * 13 + v] = p[v] + bl[v];
        }
    }
}

// ---------------- scatter: out[b,t,:] = lu[tok[b,t]*128 + t, :] ------------
__global__ __launch_bounds__(256) void scatter_kernel(const float* __restrict__ lu,
                                                      const int* __restrict__ tok,
                                                      float* __restrict__ out) {
    unsigned int i = blockIdx.x * 256 + threadIdx.x;   // < 851968 exactly
    unsigned int bt = i / 13u;
    unsigned int vv = i - bt * 13u;
    int v = tok[bt];
    int t = (int)(bt & 127u);
    out[i] = lu[(size_t)((v << 7) + t) * 13 + vv];
}

// ---------------- loss over (b, t=127) rows --------------------------------
__global__ void loss_kernel(const float* __restrict__ lu,
                            const int* __restrict__ tok,
                            const int* __restrict__ label,
                            float* __restrict__ out) {
    const int tid = threadIdx.x;
    float acc = 0.f;
    for (int b = tid; b < 512; b += 256) {
        int v = tok[b * 128 + 127];
        const float* lg = lu + (size_t)((v << 7) + 127) * 13;
        float mx = lg[0];
        #pragma unroll
        for (int vv = 1; vv < 13; vv++) mx = fmaxf(mx, lg[vv]);
        float den = 0.f;
        #pragma unroll
        for (int vv = 0; vv < 13; vv++) den += expf(lg[vv] - mx);
        int lab = label[b];
        acc += -(lg[lab] - mx - logf(den));
    }
    #pragma unroll
    for (int o = 32; o > 0; o >>= 1) acc += __shfl_xor(acc, o);
    __shared__ float red[4];
    if ((tid & 63) == 0) red[tid >> 6] = acc;
    __syncthreads();
    if (tid == 0) out[0] = (red[0] + red[1] + red[2] + red[3]) * (1.f / 512.f);
}

// ---------------------------------------------------------------------------
extern "C" void kernel_launch(void* const* d_in, const int* in_sizes, int n_in,
                              void* d_out, int out_size, void* d_ws, size_t ws_size,
                              hipStream_t stream) {
    const int*   tok   = (const int*)d_in[0];
    const int*   label = (const int*)d_in[1];
    const float* wte   = (const float*)d_in[2];
    const float* wpe   = (const float*)d_in[3];
    const float* Wq    = (const float*)d_in[4];
    const float* bq    = (const float*)d_in[5];
    const float* Wk    = (const float*)d_in[6];
    const float* bk    = (const float*)d_in[7];
    const float* Wv    = (const float*)d_in[8];
    const float* bv    = (const float*)d_in[9];
    const float* Wo    = (const float*)d_in[10];
    const float* bo    = (const float*)d_in[11];
    const float* ln_g  = (const float*)d_in[12];
    const float* ln_b  = (const float*)d_in[13];
    const float* Wlm   = (const float*)d_in[14];
    const float* blm   = (const float*)d_in[15];
    float* out = (float*)d_out;

    char* ws = (char*)d_ws;
    ushort* xbf   = (ushort*)(ws);                 // 1,703,936 B
    ushort* wqkvT = (ushort*)(ws + 1703936);       // 9,437,184 B
    ushort* woT   = (ushort*)(ws + 11141120);      // 3,145,728 B
    ushort* qkv_u = (ushort*)(ws + 14286848);      // 5,111,808 B
    ushort* tmp   = qkv_u;                         // alias (sequential-safe)
    ushort* hid_u = (ushort*)(ws + 19398656);      // 1,703,936 B
    float*  lu    = (float*) (ws + 21102592);      //    86,528 B
    float*  ps    = (float*) (ws + 21189120);      //    26,624 B
    float*  pss   = (float*) (ws + 21215744);      //    26,624 B

    prep_weights<<<1536, 256, 0, stream>>>(Wq, Wk, Wv, Wo, wqkvT, woT);
    build_xu<<<416, 256, 0, stream>>>(wte, wpe, xbf);

    for (int l = 0; l < 6; l++) {
        gemm_qkv_kernel<<<dim3(26, 12), 256, 0, stream>>>(
            xbf, wqkvT + (size_t)l * 786432,
            bq + l * 512, bk + l * 512, bv + l * 512, qkv_u);
        attn_kernel<<<416, 256, 0, stream>>>(qkv_u, hid_u);
        proj_gemm_kernel<<<dim3(52, 4), 256, 0, stream>>>(
            hid_u, woT + (size_t)l * 262144, bo + l * 512, xbf, tmp, ps, pss);
        ln_finalize_kernel<<<416, 256, 0, stream>>>(
            tmp, ps, pss, ln_g + l * 512, ln_b + l * 512, xbf);
    }

    logits_kernel<<<52, 256, 0, stream>>>(xbf, Wlm, blm, lu);
    scatter_kernel<<<3328, 256, 0, stream>>>(lu, tok, out);
    loss_kernel<<<1, 256, 0, stream>>>(lu, tok, label, out + 851968);
}